// Round 12
// baseline (228.886 us; speedup 1.0000x reference)
//
#include <hip/hip_runtime.h>

// Problem: y = relu(x @ (w1*m)^T + b1) @ (w2*m^T)^T + b2
// x:[131072,256] f32, w1:[1024,256], b1:[1024], w2:[256,1024], b2:[256], mask:[1024,256] i32
// bf16 MFMA 32x32x16. R12: 1-wave/SIMD big-tile quadrant.
// Evidence R0-R11: at 2 waves/SIMD (256-reg budget) the kernel plateaus at ~160us with
// no pipe >50% -- per-wave serial structure binds, and every ILP/staging/barrier lever
// is exhausted. This round trades TLP for per-wave intensity: 64 rows/wave (2 row-groups
// of 32, strictly sequential), 4 waves x 64 rows = MT=256 per 256-thread block,
// __launch_bounds__(256,1) -> up to 512 regs/wave (xf 128 + acc 256 + h 32 + ~30 temps
// ~ 446 <= m08's 450 no-spill bound). 64 MFMAs/subchunk/wave own the SIMD's matrix pipe;
// LDS reads/row halve. Bias folded into fc1 accumulator init (C-in = bias, rg-invariant).
// Ledger: direct-global fc2-B latency-toxic (R2); block-shared Hc col-split (R4-);
// in-reg pack +2% conflicts->0 (R5); convoy fences -18% (R6); phase-halving +2% (R9);
// merged-loop ILP at 256-reg cap -> spills (R10-); staging-halving neutral (R11).

#define D_MODEL 256
#define D_HID   1024
#define MT      256      // rows per block (4 waves x 64 rows)
#define NPHASE  16       // staging phases (64 hidden each)
#define SUBC_ELEMS 8192  // 32*256 bf16 elems per 32-hidden sub-chunk per weight (16 KB)

typedef __attribute__((ext_vector_type(8))) short short8;
typedef __attribute__((ext_vector_type(16))) float f32x16;
typedef __attribute__((ext_vector_type(4))) unsigned int uint4v;

__device__ __forceinline__ unsigned short f2bf(float f) {
  union { float f; unsigned int u; } v; v.f = f;
  unsigned int u = v.u;
  return (unsigned short)((u + 0x7FFFu + ((u >> 16) & 1u)) >> 16);  // RNE
}

__device__ __forceinline__ unsigned cvtpk_bf16(float lo, float hi) {
  unsigned r;
  asm("v_cvt_pk_bf16_f32 %0, %1, %2" : "=v"(r) : "v"(lo), "v"(hi));
  return r;
}

__device__ __forceinline__ void plswap(unsigned &a, unsigned &b) {
  asm("v_permlane32_swap_b32 %0, %1" : "+v"(a), "+v"(b));
}

__device__ __forceinline__ void async16(void* lds, const void* g) {
  __builtin_amdgcn_global_load_lds(
      (const __attribute__((address_space(1))) unsigned int*)g,
      (__attribute__((address_space(3))) unsigned int*)lds,
      16, 0, 0);
}

// ---------------- prep: mask+cast+swizzle weights into 32x32x16 B-frag order --------
// W1p slot t = (c*16+kf)*64+lane holds W1eff[h=c*32+(lane&31)][k=kf*16+(lane>>5)*8+j], j=0..7
// W2p slot s = ((c*8+cf)*2+kf2)*64+lane holds W2eff[n=cf*32+(lane&31)][h=c*32+kf2*16+(lane>>5)*8+j]
__global__ __launch_bounds__(256) void prep_weights(
    const float* __restrict__ w1, const float* __restrict__ w2,
    const int* __restrict__ mask,
    unsigned short* __restrict__ W1p, unsigned short* __restrict__ W2p)
{
  int t = blockIdx.x * 256 + threadIdx.x;   // 0..65535
  if (t < 32768) {
    int c    = t >> 10;
    int kf   = (t >> 6) & 15;
    int lane = t & 63;
    int h = c * 32 + (lane & 31);
    int k = kf * 16 + (lane >> 5) * 8;
    const float* wp = w1 + h * 256 + k;
    const int*   mp = mask + h * 256 + k;
    short8 v;
    #pragma unroll
    for (int j = 0; j < 8; ++j) v[j] = (short)(mp[j] ? f2bf(wp[j]) : 0);
    *(short8*)(W1p + (size_t)t * 8) = v;
  } else {
    int s    = t - 32768;
    int c    = s >> 10;
    int cf   = (s >> 7) & 7;
    int kf2  = (s >> 6) & 1;
    int lane = s & 63;
    int n = cf * 32 + (lane & 31);
    int h = c * 32 + kf2 * 16 + (lane >> 5) * 8;
    short8 v;
    #pragma unroll
    for (int j = 0; j < 8; ++j)
      v[j] = (short)(mask[(h + j) * 256 + n] ? f2bf(w2[n * 1024 + h + j]) : 0);
    *(short8*)(W2p + (size_t)s * 8) = v;
  }
}

// ---------------- fused main kernel ----------------
__global__ __launch_bounds__(256, 1) void ffd_fused(
    const float* __restrict__ X, const float* __restrict__ b1,
    const float* __restrict__ b2,
    const unsigned short* __restrict__ W1p, const unsigned short* __restrict__ W2p,
    float* __restrict__ Y)
{
  __shared__ unsigned short sW1[2][2 * SUBC_ELEMS];  // 64 KB dbuf, 64-hidden phases
  __shared__ unsigned short sW2[2][2 * SUBC_ELEMS];  // 64 KB dbuf
  __shared__ float sB1[D_HID];                       // 4 KB, b1 staged once

  const int tid  = threadIdx.x;                // 0..255
  const int lane = tid & 63;
  const int w    = tid >> 6;                   // 0..3
  const int l32  = lane & 31;
  const int q2   = lane >> 5;

  const long rowBase = (long)blockIdx.x * MT + w * 64;   // this wave's 64 rows

  // X fragments for BOTH row-groups: xf[rg][kf][j] = X[rowBase+rg*32+l32][kf*16+q2*8+j]
  short8 xf[2][16];
  #pragma unroll
  for (int rg = 0; rg < 2; ++rg) {
    const float* xrow = X + (rowBase + rg * 32 + l32) * D_MODEL;
    #pragma unroll
    for (int kf = 0; kf < 16; ++kf) {
      const float4 f0 = *(const float4*)(xrow + kf * 16 + q2 * 8);
      const float4 f1 = *(const float4*)(xrow + kf * 16 + q2 * 8 + 4);
      short8 v;
      v[0] = (short)f2bf(f0.x); v[1] = (short)f2bf(f0.y);
      v[2] = (short)f2bf(f0.z); v[3] = (short)f2bf(f0.w);
      v[4] = (short)f2bf(f1.x); v[5] = (short)f2bf(f1.y);
      v[6] = (short)f2bf(f1.z); v[7] = (short)f2bf(f1.w);
      xf[rg][kf] = v;
    }
  }

  f32x16 acc[2][8];
  #pragma unroll
  for (int rg = 0; rg < 2; ++rg)
    #pragma unroll
    for (int i = 0; i < 8; ++i)
      #pragma unroll
      for (int j = 0; j < 16; ++j) acc[rg][i][j] = 0.f;

  // prologue: stage b1 (16B/lane) + phase 0 into buffer 0
  async16(&sB1[tid * 4], b1 + tid * 4);
  {
    // 256 threads x 16B = 4KB/round; 8 rounds = 32KB per weight buffer
    const unsigned short* g1 = W1p + tid * 8;
    const unsigned short* g2 = W2p + tid * 8;
    #pragma unroll
    for (int i = 0; i < 8; ++i) {
      async16(&sW1[0][i * 2048 + tid * 8], g1 + i * 2048);
      async16(&sW2[0][i * 2048 + tid * 8], g2 + i * 2048);
    }
  }
  __syncthreads();   // phase 0 + b1 staged

  for (int C = 0; C < NPHASE; ++C) {
    const int cur = C & 1;

    // stage(C+1) into the other buffer; drains at the end-of-phase barrier,
    // hidden under ~6k cyc of compute
    if (C + 1 < NPHASE) {
      const unsigned short* g1 = W1p + (size_t)(C + 1) * (2 * SUBC_ELEMS) + tid * 8;
      const unsigned short* g2 = W2p + (size_t)(C + 1) * (2 * SUBC_ELEMS) + tid * 8;
      unsigned short* d1 = &sW1[cur ^ 1][tid * 8];
      unsigned short* d2 = &sW2[cur ^ 1][tid * 8];
      #pragma unroll
      for (int i = 0; i < 8; ++i) {
        async16(d1 + i * 2048, g1 + i * 2048);
        async16(d2 + i * 2048, g2 + i * 2048);
      }
    }

    // -------- two 32-hidden sub-chunks --------
    #pragma unroll
    for (int p = 0; p < 2; ++p) {
      const int c = C * 2 + p;   // global sub-chunk 0..31
      const unsigned short* w1c = &sW1[cur][p * SUBC_ELEMS];
      const unsigned short* w2c = &sW2[cur][p * SUBC_ELEMS];

      // bias (rg-invariant: indexed by hidden unit only): bb[g][e] = b1[c*32+4*q2+8*g+e]
      float4 bb[4];
      #pragma unroll
      for (int g = 0; g < 4; ++g)
        bb[g] = *(const float4*)&sB1[c * 32 + 4 * q2 + 8 * g];

      // ---- row-groups strictly sequential (register peak control) ----
      #pragma unroll
      for (int rg = 0; rg < 2; ++rg) {
        // fc1 SWAPPED: Hc^T tile = W1c @ X^T; C-in preloaded with bias (h0) / 0 (h1)
        f32x16 h0, h1;
        #pragma unroll
        for (int r = 0; r < 16; ++r) { h0[r] = bb[r >> 2][r & 3]; h1[r] = 0.f; }
        __builtin_amdgcn_s_setprio(1);
        #pragma unroll
        for (int kf = 0; kf < 8; ++kf) {
          short8 wa = *(const short8*)&w1c[kf * 512 + lane * 8];
          short8 wb = *(const short8*)&w1c[(kf + 8) * 512 + lane * 8];
          h0 = __builtin_amdgcn_mfma_f32_32x32x16_bf16(wa, xf[rg][kf],     h0, 0, 0, 0);
          h1 = __builtin_amdgcn_mfma_f32_32x32x16_bf16(wb, xf[rg][kf + 8], h1, 0, 0, 0);
        }
        __builtin_amdgcn_s_setprio(0);

        // relu in C-space (bias already in h0)
        float v[16];
        #pragma unroll
        for (int r = 0; r < 16; ++r) {
          float t = h0[r] + h1[r];
          v[r] = t > 0.f ? t : 0.f;
        }

        // pack to fc2 A-frags in-register (cvt_pk + permlane32_swap)
        unsigned W0 = cvtpk_bf16(v[0],  v[1]),  W1 = cvtpk_bf16(v[2],  v[3]);
        unsigned W2 = cvtpk_bf16(v[4],  v[5]),  W3 = cvtpk_bf16(v[6],  v[7]);
        unsigned W4 = cvtpk_bf16(v[8],  v[9]),  W5 = cvtpk_bf16(v[10], v[11]);
        unsigned W6 = cvtpk_bf16(v[12], v[13]), W7 = cvtpk_bf16(v[14], v[15]);
        plswap(W0, W2); plswap(W1, W3); plswap(W4, W6); plswap(W5, W7);
        union { uint4v u; short8 s; } A0, A1;
        A0.u = (uint4v){W0, W1, W2, W3};
        A1.u = (uint4v){W4, W5, W6, W7};

        // fc2: acc[rg][32 rows][256 cols] += Hc @ W2c^T
        __builtin_amdgcn_s_setprio(1);
        #pragma unroll
        for (int cf = 0; cf < 8; ++cf) {
          short8 b0  = *(const short8*)&w2c[(cf * 2 + 0) * 512 + lane * 8];
          short8 b1f = *(const short8*)&w2c[(cf * 2 + 1) * 512 + lane * 8];
          acc[rg][cf] = __builtin_amdgcn_mfma_f32_32x32x16_bf16(A0.s, b0,  acc[rg][cf], 0, 0, 0);
          acc[rg][cf] = __builtin_amdgcn_mfma_f32_32x32x16_bf16(A1.s, b1f, acc[rg][cf], 0, 0, 0);
        }
        __builtin_amdgcn_s_setprio(0);
      }
    }

    __syncthreads();  // buf[cur] fully consumed; stage(C+1) landed
  }

  // epilogue: + b2, store fp32 (coalesced along l32)
  #pragma unroll
  for (int rg = 0; rg < 2; ++rg) {
    #pragma unroll
    for (int cf = 0; cf < 8; ++cf) {
      int col = cf * 32 + l32;
      float bias = b2[col];
      #pragma unroll
      for (int r = 0; r < 16; ++r) {
        long row = rowBase + rg * 32 + (r & 3) + 8 * (r >> 2) + 4 * q2;
        Y[row * D_MODEL + col] = acc[rg][cf][r] + bias;
      }
    }
  }
}

extern "C" void kernel_launch(void* const* d_in, const int* in_sizes, int n_in,
                              void* d_out, int out_size, void* d_ws, size_t ws_size,
                              hipStream_t stream) {
  const float* x    = (const float*)d_in[0];
  const float* w1   = (const float*)d_in[1];
  const float* b1   = (const float*)d_in[2];
  const float* w2   = (const float*)d_in[3];
  const float* b2   = (const float*)d_in[4];
  const int*   mask = (const int*)d_in[5];

  unsigned short* W1p = (unsigned short*)d_ws;          // 512 KB
  unsigned short* W2p = W1p + (size_t)D_HID * D_MODEL;  // 512 KB
  float* Y = (float*)d_out;

  prep_weights<<<256, 256, 0, stream>>>(w1, w2, mask, W1p, W2p);
  ffd_fused<<<131072 / MT, 256, 0, stream>>>(x, b1, b2, W1p, W2p, Y);
}

// Round 13
// 151.660 us; speedup vs baseline: 1.5092x; 1.5092x over previous
//
#include <hip/hip_runtime.h>

// Problem: y = relu(x @ (w1*m)^T + b1) @ (w2*m^T)^T + b2
// x:[131072,256] f32, w1:[1024,256], b1:[1024], w2:[256,1024], b2:[256], mask:[1024,256] i32
// bf16 MFMA 32x32x16, MT=128 (4 waves x 32 rows), 16 staging phases of 64 hidden.
// R13 = R9 (best: 160.0us) + two critical-path VALU cuts:
//  (1) bias via fc1 MFMA C-in (h0 init = bias; validated in R12) -- saves 16 movs+16 adds
//  (2) split-pack pipelining: pack A0 -> 8 A0-MFMAs -> pack A1 -> 8 A1-MFMAs
//      (halves the serial VALU section between fc1 and fc2)
// Ledger: direct-global fc2-B latency-toxic (R2); dbuf-late-drain neutral (R3);
// block-shared Hc col-split regression (R4); in-reg pack +2% conflicts->0 (R5);
// convoy barriers/fences -18% (R6); phase-halving +2% (R9); merged-loop ILP
// at 256-reg cap -> spills (R10); staging-halving/dbuf neutral (R11);
// 1-wave/SIMD 64-rows quadrant -23% latency-exposed (R12).

#define D_MODEL 256
#define D_HID   1024
#define MT      128      // rows per block (4 waves x 32 rows)
#define NPHASE  16       // staging phases (64 hidden each)
#define SUBC_ELEMS 8192  // 32*256 bf16 elems per 32-hidden sub-chunk per weight (16 KB)

typedef __attribute__((ext_vector_type(8))) short short8;
typedef __attribute__((ext_vector_type(16))) float f32x16;
typedef __attribute__((ext_vector_type(4))) unsigned int uint4v;

__device__ __forceinline__ unsigned short f2bf(float f) {
  union { float f; unsigned int u; } v; v.f = f;
  unsigned int u = v.u;
  return (unsigned short)((u + 0x7FFFu + ((u >> 16) & 1u)) >> 16);  // RNE
}

__device__ __forceinline__ unsigned cvtpk_bf16(float lo, float hi) {
  unsigned r;
  asm("v_cvt_pk_bf16_f32 %0, %1, %2" : "=v"(r) : "v"(lo), "v"(hi));
  return r;
}

__device__ __forceinline__ void plswap(unsigned &a, unsigned &b) {
  asm("v_permlane32_swap_b32 %0, %1" : "+v"(a), "+v"(b));
}

__device__ __forceinline__ void async16(void* lds, const void* g) {
  __builtin_amdgcn_global_load_lds(
      (const __attribute__((address_space(1))) unsigned int*)g,
      (__attribute__((address_space(3))) unsigned int*)lds,
      16, 0, 0);
}

// ---------------- prep: mask+cast+swizzle weights into 32x32x16 B-frag order --------
// W1p slot t = (c*16+kf)*64+lane holds W1eff[h=c*32+(lane&31)][k=kf*16+(lane>>5)*8+j], j=0..7
// W2p slot s = ((c*8+cf)*2+kf2)*64+lane holds W2eff[n=cf*32+(lane&31)][h=c*32+kf2*16+(lane>>5)*8+j]
__global__ __launch_bounds__(256) void prep_weights(
    const float* __restrict__ w1, const float* __restrict__ w2,
    const int* __restrict__ mask,
    unsigned short* __restrict__ W1p, unsigned short* __restrict__ W2p)
{
  int t = blockIdx.x * 256 + threadIdx.x;   // 0..65535
  if (t < 32768) {
    int c    = t >> 10;
    int kf   = (t >> 6) & 15;
    int lane = t & 63;
    int h = c * 32 + (lane & 31);
    int k = kf * 16 + (lane >> 5) * 8;
    const float* wp = w1 + h * 256 + k;
    const int*   mp = mask + h * 256 + k;
    short8 v;
    #pragma unroll
    for (int j = 0; j < 8; ++j) v[j] = (short)(mp[j] ? f2bf(wp[j]) : 0);
    *(short8*)(W1p + (size_t)t * 8) = v;
  } else {
    int s    = t - 32768;
    int c    = s >> 10;
    int cf   = (s >> 7) & 7;
    int kf2  = (s >> 6) & 1;
    int lane = s & 63;
    int n = cf * 32 + (lane & 31);
    int h = c * 32 + kf2 * 16 + (lane >> 5) * 8;
    short8 v;
    #pragma unroll
    for (int j = 0; j < 8; ++j)
      v[j] = (short)(mask[(h + j) * 256 + n] ? f2bf(w2[n * 1024 + h + j]) : 0);
    *(short8*)(W2p + (size_t)s * 8) = v;
  }
}

// ---------------- fused main kernel ----------------
__global__ __launch_bounds__(256, 2) void ffd_fused(
    const float* __restrict__ X, const float* __restrict__ b1,
    const float* __restrict__ b2,
    const unsigned short* __restrict__ W1p, const unsigned short* __restrict__ W2p,
    float* __restrict__ Y)
{
  __shared__ unsigned short sW1[2 * SUBC_ELEMS];  // 32 KB: 64-hidden phase, frag order
  __shared__ unsigned short sW2[2 * SUBC_ELEMS];  // 32 KB
  __shared__ float sB1[D_HID];                    // 4 KB, b1 staged once

  const int tid  = threadIdx.x;
  const int lane = tid & 63;
  const int w    = tid >> 6;
  const int l32  = lane & 31;
  const int q2   = lane >> 5;

  const long rowBase = (long)blockIdx.x * MT + w * 32;

  // X fragments (full K=256) in registers: xf[kf][j] = X[rowBase+l32][kf*16 + q2*8 + j]
  short8 xf[16];
  const float* xrow = X + (rowBase + l32) * D_MODEL;
  #pragma unroll
  for (int kf = 0; kf < 16; ++kf) {
    const float4 f0 = *(const float4*)(xrow + kf * 16 + q2 * 8);
    const float4 f1 = *(const float4*)(xrow + kf * 16 + q2 * 8 + 4);
    short8 v;
    v[0] = (short)f2bf(f0.x); v[1] = (short)f2bf(f0.y);
    v[2] = (short)f2bf(f0.z); v[3] = (short)f2bf(f0.w);
    v[4] = (short)f2bf(f1.x); v[5] = (short)f2bf(f1.y);
    v[6] = (short)f2bf(f1.z); v[7] = (short)f2bf(f1.w);
    xf[kf] = v;
  }

  f32x16 acc[8];
  #pragma unroll
  for (int i = 0; i < 8; ++i)
    #pragma unroll
    for (int j = 0; j < 16; ++j) acc[i][j] = 0.f;

  // prologue: stage b1 once (16B/lane — required by global_load_lds)
  async16(&sB1[tid * 4], b1 + tid * 4);

  for (int C = 0; C < NPHASE; ++C) {
    __syncthreads();   // previous phase's weights fully consumed
    {
      // 16B per thread (tid*8 shorts), 8 rounds of 4KB per buffer = 32KB each
      const unsigned short* g1 = W1p + (size_t)C * (2 * SUBC_ELEMS) + tid * 8;
      const unsigned short* g2 = W2p + (size_t)C * (2 * SUBC_ELEMS) + tid * 8;
      unsigned short* d1 = &sW1[tid * 8];
      unsigned short* d2 = &sW2[tid * 8];
      #pragma unroll
      for (int i = 0; i < 8; ++i) {
        async16(d1 + i * 2048, g1 + i * 2048);
        async16(d2 + i * 2048, g2 + i * 2048);
      }
    }
    __syncthreads();   // staged (compiler drains vmcnt before barrier)

    // -------- two 32-hidden sub-chunks, strictly sequential --------
    #pragma unroll
    for (int p = 0; p < 2; ++p) {
      const int c = C * 2 + p;   // global sub-chunk 0..31
      const unsigned short* w1c = &sW1[p * SUBC_ELEMS];
      const unsigned short* w2c = &sW2[p * SUBC_ELEMS];

      // bias vectors: h-row r needs b1[c*32 + (r&3) + 8*(r>>2) + 4*q2]
      float4 bb[4];
      #pragma unroll
      for (int g = 0; g < 4; ++g)
        bb[g] = *(const float4*)&sB1[c * 32 + 4 * q2 + 8 * g];

      // fc1 SWAPPED: Hc^T tile = W1c @ X^T; lane holds C[h=crow(r,q2)][xrow=l32].
      // Bias folded into h0's C-in (saves 16 movs + 16 adds on the critical path).
      f32x16 h0, h1;
      #pragma unroll
      for (int r = 0; r < 16; ++r) { h0[r] = bb[r >> 2][r & 3]; h1[r] = 0.f; }
      __builtin_amdgcn_s_setprio(1);
      #pragma unroll
      for (int kf = 0; kf < 8; ++kf) {
        short8 wa = *(const short8*)&w1c[kf * 512 + lane * 8];
        short8 wb = *(const short8*)&w1c[(kf + 8) * 512 + lane * 8];
        h0 = __builtin_amdgcn_mfma_f32_32x32x16_bf16(wa, xf[kf],     h0, 0, 0, 0);
        h1 = __builtin_amdgcn_mfma_f32_32x32x16_bf16(wb, xf[kf + 8], h1, 0, 0, 0);
      }
      __builtin_amdgcn_s_setprio(0);

      // ---- split-pack pipelining ----
      // pack A0 (low 16 hidden) first, start its 8 MFMAs, pack A1 behind them.
      union { uint4v u; short8 s; } A0, A1;
      {
        float v0 = fmaxf(h0[0]  + h1[0],  0.f), v1 = fmaxf(h0[1]  + h1[1],  0.f);
        float v2 = fmaxf(h0[2]  + h1[2],  0.f), v3 = fmaxf(h0[3]  + h1[3],  0.f);
        float v4 = fmaxf(h0[4]  + h1[4],  0.f), v5 = fmaxf(h0[5]  + h1[5],  0.f);
        float v6 = fmaxf(h0[6]  + h1[6],  0.f), v7 = fmaxf(h0[7]  + h1[7],  0.f);
        unsigned W0 = cvtpk_bf16(v0, v1), W1 = cvtpk_bf16(v2, v3);
        unsigned W2 = cvtpk_bf16(v4, v5), W3 = cvtpk_bf16(v6, v7);
        plswap(W0, W2); plswap(W1, W3);
        A0.u = (uint4v){W0, W1, W2, W3};
      }

      __builtin_amdgcn_s_setprio(1);
      #pragma unroll
      for (int cf = 0; cf < 8; ++cf) {
        short8 b0 = *(const short8*)&w2c[(cf * 2 + 0) * 512 + lane * 8];
        acc[cf] = __builtin_amdgcn_mfma_f32_32x32x16_bf16(A0.s, b0, acc[cf], 0, 0, 0);
      }
      __builtin_amdgcn_s_setprio(0);

      {
        float v8  = fmaxf(h0[8]  + h1[8],  0.f), v9  = fmaxf(h0[9]  + h1[9],  0.f);
        float v10 = fmaxf(h0[10] + h1[10], 0.f), v11 = fmaxf(h0[11] + h1[11], 0.f);
        float v12 = fmaxf(h0[12] + h1[12], 0.f), v13 = fmaxf(h0[13] + h1[13], 0.f);
        float v14 = fmaxf(h0[14] + h1[14], 0.f), v15 = fmaxf(h0[15] + h1[15], 0.f);
        unsigned W4 = cvtpk_bf16(v8,  v9),  W5 = cvtpk_bf16(v10, v11);
        unsigned W6 = cvtpk_bf16(v12, v13), W7 = cvtpk_bf16(v14, v15);
        plswap(W4, W6); plswap(W5, W7);
        A1.u = (uint4v){W4, W5, W6, W7};
      }

      __builtin_amdgcn_s_setprio(1);
      #pragma unroll
      for (int cf = 0; cf < 8; ++cf) {
        short8 b1f = *(const short8*)&w2c[(cf * 2 + 1) * 512 + lane * 8];
        acc[cf] = __builtin_amdgcn_mfma_f32_32x32x16_bf16(A1.s, b1f, acc[cf], 0, 0, 0);
      }
      __builtin_amdgcn_s_setprio(0);
    }
  }

  // epilogue: + b2, store fp32 (coalesced along l32)
  #pragma unroll
  for (int cf = 0; cf < 8; ++cf) {
    int col = cf * 32 + l32;
    float bias = b2[col];
    #pragma unroll
    for (int r = 0; r < 16; ++r) {
      long row = rowBase + (r & 3) + 8 * (r >> 2) + 4 * q2;
      Y[row * D_MODEL + col] = acc[cf][r] + bias;
    }
  }
}

extern "C" void kernel_launch(void* const* d_in, const int* in_sizes, int n_in,
                              void* d_out, int out_size, void* d_ws, size_t ws_size,
                              hipStream_t stream) {
  const float* x    = (const float*)d_in[0];
  const float* w1   = (const float*)d_in[1];
  const float* b1   = (const float*)d_in[2];
  const float* w2   = (const float*)d_in[3];
  const float* b2   = (const float*)d_in[4];
  const int*   mask = (const int*)d_in[5];

  unsigned short* W1p = (unsigned short*)d_ws;          // 512 KB
  unsigned short* W2p = W1p + (size_t)D_HID * D_MODEL;  // 512 KB
  float* Y = (float*)d_out;

  prep_weights<<<256, 256, 0, stream>>>(w1, w2, mask, W1p, W2p);
  ffd_fused<<<131072 / MT, 256, 0, stream>>>(x, b1, b2, W1p, W2p, Y);
}